// Round 1
// baseline (190.776 us; speedup 1.0000x reference)
//
#include <hip/hip_runtime.h>

// PositionwiseMaxPool2D: x [32,128,128,64] f32 NHWC, 2x2/stride2 window.
// Per output (b,oh,ow): k* = argmax_k sum_c x[window k][c]^2 (first-wins),
// out[b,oh,ow,:] = x[winning cell][:].
//
// One wave handles TWO adjacent outputs (ow pair): the window rows span
// 256 contiguous floats -> 1 coalesced dwordx4 load per row per wave.

#define IB 32
#define IH 128
#define IW 128
#define IC 64
#define OH 64
#define OW 64

__global__ __launch_bounds__(256) void pos_maxpool_kernel(
    const float* __restrict__ x, float* __restrict__ out) {
  const int tid = threadIdx.x;
  const int l = tid & 63;                       // lane
  const int wid = (blockIdx.x << 2) + (tid >> 6);  // global wave id, [0, 65536)

  // wave id -> (b, oh, ow2) with ow2 = output-pair index in [0,32)
  const int ow2 = wid & 31;
  const int t = wid >> 5;
  const int oh = t & 63;
  const int b = t >> 6;

  const int h0 = oh * 2;
  const int w0 = ow2 * 4;  // first of 4 input w-positions covered by this wave

  // row segment base (in floats); 256 consecutive floats per row
  const long long row0 = (((long long)(b * IH + h0) * IW) + w0) * IC;
  const long long row1 = row0 + (long long)IW * IC;

  const float4* __restrict__ x4 = (const float4*)x;
  // lane l covers floats [4l, 4l+4) of the segment:
  //   w-position g = l>>4 (0..3), channels c = 4*(l&15) .. +3
  float4 a0 = x4[(row0 >> 2) + l];
  float4 a1 = x4[(row1 >> 2) + l];

  float s0 = a0.x * a0.x + a0.y * a0.y + a0.z * a0.z + a0.w * a0.w;
  float s1 = a1.x * a1.x + a1.y * a1.y + a1.z * a1.z + a1.w * a1.w;

  // sum-of-squares over channels: butterfly within each 16-lane group.
  // Butterfly keeps the value bit-identical across all lanes of a group.
#pragma unroll
  for (int off = 1; off < 16; off <<= 1) {
    s0 += __shfl_xor(s0, off, 64);
    s1 += __shfl_xor(s1, off, 64);
  }
  // partner column's norms (group g ^ 1, same wave half)
  const float o0 = __shfl_xor(s0, 16, 64);
  const float o1 = __shfl_xor(s1, 16, 64);

  // lane's own data is window column j = p within its output
  const int p = (l >> 4) & 1;
  const float n00 = p ? o0 : s0;  // (i=0, j=0)
  const float n01 = p ? s0 : o0;  // (i=0, j=1)
  const float n10 = p ? o1 : s1;  // (i=1, j=0)
  const float n11 = p ? s1 : o1;  // (i=1, j=1)

  // argmax over k = i*2 + j, strict > == jnp.argmax first-occurrence
  int k = 0;
  float best = n00;
  if (n01 > best) { best = n01; k = 1; }
  if (n10 > best) { best = n10; k = 2; }
  if (n11 > best) { best = n11; k = 3; }
  const int istar = k >> 1;
  const int jstar = k & 1;

  // lanes whose column matches the winner store their float4 (half-wave
  // masked store is still one coalesced 512B transaction for the wave)
  if (p == jstar) {
    const int h = l >> 5;            // which output of the pair
    const int ow = ow2 * 2 + h;
    const int c4 = l & 15;           // float4 index along channels
    const float4 v = istar ? a1 : a0;
    float4* __restrict__ o4 = (float4*)out;
    const long long oidx =
        (((long long)(b * OH + oh) * OW) + ow) * (IC / 4) + c4;
    o4[oidx] = v;
  }
}

extern "C" void kernel_launch(void* const* d_in, const int* in_sizes, int n_in,
                              void* d_out, int out_size, void* d_ws,
                              size_t ws_size, hipStream_t stream) {
  const float* x = (const float*)d_in[0];
  float* out = (float*)d_out;
  // 65536 waves total = 16384 blocks x 4 waves
  pos_maxpool_kernel<<<16384, 256, 0, stream>>>(x, out);
}